// Round 10
// baseline (509.471 us; speedup 1.0000x reference)
//
#include <hip/hip_runtime.h>

// Actor: state[B,10] -> 4x GRU dir(H=10,T=5,in=1) -> concat[40] -> l1(40->20,selu) -> l2(20->2) -> clip
// R10 = R8 restored verbatim (last known-good, 507us). R9's peel+ping-pong failed correctness
// for reasons not identifiable by inspection (suspected codegen hazard in the macro-expanded
// peel); reverting to the proven structure: fp32, 4 dirs x 4 rows/lane, v_pk_fma_f32,
// streaming epilogue. Exact math; absmax = bf16-ref floor.

#define NH 10

typedef float f32x2 __attribute__((ext_vector_type(2)));
struct __align__(16) q2 { f32x2 lo, hi; };   // one ds_read_b128 = two even-aligned pairs

__device__ __forceinline__ float frcp(float x) { return __builtin_amdgcn_rcpf(x); }
__device__ __forceinline__ float fexp2(float x) { return __builtin_amdgcn_exp2f(x); }
__device__ __forceinline__ float fexp(float x) { return __expf(x); }

// d = a * b.lo + c
__device__ __forceinline__ f32x2 pk_fma_lo(f32x2 a, f32x2 b, f32x2 c) {
    f32x2 d;
    asm("v_pk_fma_f32 %0, %1, %2, %3 op_sel_hi:[1,0,1]" : "=v"(d) : "v"(a), "v"(b), "v"(c));
    return d;
}
// d = a * b.hi + c
__device__ __forceinline__ f32x2 pk_fma_hi(f32x2 a, f32x2 b, f32x2 c) {
    f32x2 d;
    asm("v_pk_fma_f32 %0, %1, %2, %3 op_sel:[0,1,0] op_sel_hi:[1,1,1]" : "=v"(d) : "v"(a), "v"(b), "v"(c));
    return d;
}
// d = a * b.hi + c.lo   (bias-init: xt*wih + bias, bias in c.lo)
__device__ __forceinline__ f32x2 pk_fma_bh_cl(f32x2 a, f32x2 b, f32x2 c) {
    f32x2 d;
    asm("v_pk_fma_f32 %0, %1, %2, %3 op_sel:[0,1,0] op_sel_hi:[1,1,0]" : "=v"(d) : "v"(a), "v"(b), "v"(c));
    return d;
}
// d = a * b.lo + c.lo
__device__ __forceinline__ f32x2 pk_fma_bl_cl(f32x2 a, f32x2 b, f32x2 c) {
    f32x2 d;
    asm("v_pk_fma_f32 %0, %1, %2, %3 op_sel_hi:[1,0,0]" : "=v"(d) : "v"(a), "v"(b), "v"(c));
    return d;
}
// full packed d = a*b + c
__device__ __forceinline__ f32x2 pk_fma(f32x2 a, f32x2 b, f32x2 c) {
    f32x2 d;
    asm("v_pk_fma_f32 %0, %1, %2, %3" : "=v"(d) : "v"(a), "v"(b), "v"(c));
    return d;
}

// acc += dot(w[1..9], hh[1..9]) given quads q1=(w0..3) q2_=(w4..7) q3=(w8,w9,-,-)
#define PDOT9(acc, hh, q1, q2_, q3)                  \
    acc = pk_fma_hi(hh[1], (q1).lo, acc);            \
    acc = pk_fma_lo(hh[2], (q1).hi, acc);            \
    acc = pk_fma_hi(hh[3], (q1).hi, acc);            \
    acc = pk_fma_lo(hh[4], (q2_).lo, acc);           \
    acc = pk_fma_hi(hh[5], (q2_).lo, acc);           \
    acc = pk_fma_lo(hh[6], (q2_).hi, acc);           \
    acc = pk_fma_hi(hh[7], (q2_).hi, acc);           \
    acc = pk_fma_lo(hh[8], (q3).lo, acc);            \
    acc = pk_fma_hi(hh[9], (q3).lo, acc);

#define LDQ(p) (*(const q2*)(p))

__global__ __launch_bounds__(256) void actor_kernel(
    const float* __restrict__ state,
    const float* __restrict__ wih0, const float* __restrict__ whh0,
    const float* __restrict__ bih0, const float* __restrict__ bhh0,
    const float* __restrict__ wih1, const float* __restrict__ whh1,
    const float* __restrict__ bih1, const float* __restrict__ bhh1,
    const float* __restrict__ wih2, const float* __restrict__ whh2,
    const float* __restrict__ bih2, const float* __restrict__ bhh2,
    const float* __restrict__ wih3, const float* __restrict__ whh3,
    const float* __restrict__ bih3, const float* __restrict__ bhh3,
    const float* __restrict__ l1w, const float* __restrict__ l1b,
    const float* __restrict__ l2w, const float* __restrict__ l2b,
    float* __restrict__ out, int Btot)
{
    // Row g (48B): [0..9]=whh*sc, [10]=bias*sc ((bih+bhh) r/z, bhh n), [11]=wih*sc.
    // Dir stride 360 dwords -> quad lanes at bank offsets {0,8,16,24}: conflict-free b128.
    __shared__ __align__(16) float s_w[4][360];
    __shared__ __align__(8) f32x2 s_bihn2[4][10];   // bih n-gate * 2log2e, duplicated {v,v}
    __shared__ __align__(16) float s_l1w[20][48];   // per-dir 12-dword chunks, zero-padded
    __shared__ float s_l1b[20];
    __shared__ __align__(8) f32x2 s_l2w2[2][20];    // duplicated {v,v}
    __shared__ float s_l2b[2];

    const int tid = threadIdx.x;
    const float NL2E = -1.4426950408889634f;   // -log2(e)   (r,z rows)
    const float P2L2E = 2.8853900817779268f;   // 2*log2(e)  (n rows)

#define STAGE_DIR(d, wihP, whhP, bihP, bhhP)                                   \
    for (int i = tid; i < 360; i += 256) {                                     \
        int g = i / 12, s = i % 12;                                            \
        float sc = (g < 20) ? NL2E : P2L2E;                                    \
        float v;                                                               \
        if (s < 10)       v = whhP[g * 10 + s] * sc;                           \
        else if (s == 10) v = ((g < 20) ? (bihP[g] + bhhP[g]) : bhhP[g]) * sc; \
        else              v = wihP[g] * sc;                                    \
        s_w[d][g * 12 + s] = v;                                                \
    }                                                                          \
    for (int i = tid; i < 10; i += 256) {                                      \
        float v = bihP[20 + i] * P2L2E;                                        \
        s_bihn2[d][i] = (f32x2){v, v};                                         \
    }

    STAGE_DIR(0, wih0, whh0, bih0, bhh0)
    STAGE_DIR(1, wih1, whh1, bih1, bhh1)
    STAGE_DIR(2, wih2, whh2, bih2, bhh2)
    STAGE_DIR(3, wih3, whh3, bih3, bhh3)
#undef STAGE_DIR
    for (int i = tid; i < 960; i += 256) {
        int o = i / 48, c = i % 48, dd = c / 12, jj = c % 12;
        s_l1w[o][c] = (jj < 10) ? l1w[o * 40 + dd * 10 + jj] : 0.0f;
    }
    for (int i = tid; i < 20; i += 256) s_l1b[i] = l1b[i];
    for (int i = tid; i < 40; i += 256) {
        float v = l2w[i];
        s_l2w2[i / 20][i % 20] = (f32x2){v, v};
    }
    for (int i = tid; i < 2; i += 256) s_l2b[i] = l2b[i];
    __syncthreads();

    const int q = tid >> 2;
    const int d = tid & 3;            // 0=g1 fwd, 1=g1 bwd, 2=g2 fwd, 3=g2 bwd
    // 4 rows per lane: pair P = {base, base+1}, pair Q = {base+2, base+3}
    long long base = (long long)blockIdx.x * 256 + 4 * q;
    long long r0 = base, r1 = base + 1, r2 = base + 2, r3 = base + 3;
    const bool v01 = (r1 < Btot), v23 = (r3 < Btot);
    if (r0 >= Btot) r0 = Btot - 1;
    if (r1 >= Btot) r1 = Btot - 1;
    if (r2 >= Btot) r2 = Btot - 1;
    if (r3 >= Btot) r3 = Btot - 1;

    // packed x queues
    f32x2 xqp[5], xqq[5];
    {
        const int off = (d & 2) ? 5 : 0;
        const float* p0 = state + r0 * 10 + off;
        const float* p1 = state + r1 * 10 + off;
        const float* p2 = state + r2 * 10 + off;
        const float* p3 = state + r3 * 10 + off;
        const int rev = d & 1;
#pragma unroll
        for (int i = 0; i < 5; ++i) {
            int k = rev ? (4 - i) : i;
            xqp[i] = (f32x2){p0[k], p1[k]};
            xqq[i] = (f32x2){p2[k], p3[k]};
        }
    }

    const float* wb0 = &s_w[d][0];
    const f32x2* bn2 = &s_bihn2[d][0];

    f32x2 hp[NH], hq[NH];
#pragma unroll
    for (int j = 0; j < NH; ++j) { hp[j] = (f32x2){0.0f, 0.0f}; hq[j] = (f32x2){0.0f, 0.0f}; }

    unsigned hoff = 0;  // opaque 0: blocks LICM/CSE of weight loads across t-steps
#pragma unroll 1
    for (int tt = 0; tt < 5; ++tt) {
        asm volatile("" : "+v"(hoff));
        const float* wb = wb0 + hoff;
        const f32x2 xtp = xqp[0], xtq = xqq[0];
#pragma unroll
        for (int i = 0; i < 4; ++i) { xqp[i] = xqp[i + 1]; xqq[i] = xqq[i + 1]; }

        f32x2 hnp[NH], hnq[NH];
#pragma unroll
        for (int j = 0; j < NH; ++j) {
            const float* rp = wb + j * 12;
            const float* zp = wb + (j + 10) * 12;
            const float* np = wb + (j + 20) * 12;
            q2 rq0 = LDQ(rp), rq1 = LDQ(rp + 4), rq2 = LDQ(rp + 8);
            q2 zq0 = LDQ(zp), zq1 = LDQ(zp + 4), zq2 = LDQ(zp + 8);
            q2 nq0 = LDQ(np), nq1 = LDQ(np + 4), nq2 = LDQ(np + 8);
            const f32x2 bnj = bn2[j];

            // pair P
            f32x2 arP = pk_fma_bh_cl(xtp, rq2.hi, rq2.hi);
            arP = pk_fma_lo(hp[0], rq0.lo, arP);
            PDOT9(arP, hp, rq0, rq1, rq2)
            f32x2 azP = pk_fma_bh_cl(xtp, zq2.hi, zq2.hi);
            azP = pk_fma_lo(hp[0], zq0.lo, azP);
            PDOT9(azP, hp, zq0, zq1, zq2)
            f32x2 anP = pk_fma_bl_cl(hp[0], nq0.lo, nq2.hi);
            PDOT9(anP, hp, nq0, nq1, nq2)
            f32x2 xnP = pk_fma_bh_cl(xtp, nq2.hi, bnj);

            // pair Q (reuses the 9 loaded quads)
            f32x2 arQ = pk_fma_bh_cl(xtq, rq2.hi, rq2.hi);
            arQ = pk_fma_lo(hq[0], rq0.lo, arQ);
            PDOT9(arQ, hq, rq0, rq1, rq2)
            f32x2 azQ = pk_fma_bh_cl(xtq, zq2.hi, zq2.hi);
            azQ = pk_fma_lo(hq[0], zq0.lo, azQ);
            PDOT9(azQ, hq, zq0, zq1, zq2)
            f32x2 anQ = pk_fma_bl_cl(hq[0], nq0.lo, nq2.hi);
            PDOT9(anQ, hq, nq0, nq1, nq2)
            f32x2 xnQ = pk_fma_bh_cl(xtq, nq2.hi, bnj);

            f32x2 rrP, zzP, eP, nnP, rrQ, zzQ, eQ, nnQ;
            rrP.x = frcp(1.0f + fexp2(arP.x)); rrP.y = frcp(1.0f + fexp2(arP.y));
            zzP.x = frcp(1.0f + fexp2(azP.x)); zzP.y = frcp(1.0f + fexp2(azP.y));
            eP.x = fexp2(fmaf(rrP.x, anP.x, xnP.x)); eP.y = fexp2(fmaf(rrP.y, anP.y, xnP.y));
            nnP.x = fmaf(-2.0f, frcp(eP.x + 1.0f), 1.0f);
            nnP.y = fmaf(-2.0f, frcp(eP.y + 1.0f), 1.0f);
            rrQ.x = frcp(1.0f + fexp2(arQ.x)); rrQ.y = frcp(1.0f + fexp2(arQ.y));
            zzQ.x = frcp(1.0f + fexp2(azQ.x)); zzQ.y = frcp(1.0f + fexp2(azQ.y));
            eQ.x = fexp2(fmaf(rrQ.x, anQ.x, xnQ.x)); eQ.y = fexp2(fmaf(rrQ.y, anQ.y, xnQ.y));
            nnQ.x = fmaf(-2.0f, frcp(eQ.x + 1.0f), 1.0f);
            nnQ.y = fmaf(-2.0f, frcp(eQ.y + 1.0f), 1.0f);

            hnp[j] = pk_fma(zzP, hp[j] - nnP, nnP);   // (1-z)*n + z*h
            hnq[j] = pk_fma(zzQ, hq[j] - nnQ, nnQ);
        }
#pragma unroll
        for (int j = 0; j < NH; ++j) { hp[j] = hnp[j]; hq[j] = hnq[j]; }
    }

    // Streaming epilogue: per output o, l1 partial -> quad butterfly allreduce ->
    // +bias -> SELU -> l2 accumulate. No a1[] array stays live.
    const float SC = 1.0507009873554805f;
    const float AL = 1.6732632423543772f;
    f32x2 o0P = (f32x2){s_l2b[0], s_l2b[0]};
    f32x2 o1P = (f32x2){s_l2b[1], s_l2b[1]};
    f32x2 o0Q = o0P, o1Q = o1P;
#pragma unroll
    for (int o = 0; o < 20; ++o) {
        const float* lw = &s_l1w[o][0] + d * 12;
        q2 c0 = LDQ(lw), c1 = LDQ(lw + 4), c2 = LDQ(lw + 8);
        f32x2 sP = pk_fma_bl_cl(hp[0], c0.lo, c2.hi);   // h0*w0 + 0 (pad)
        PDOT9(sP, hp, c0, c1, c2)
        f32x2 sQ = pk_fma_bl_cl(hq[0], c0.lo, c2.hi);
        PDOT9(sQ, hq, c0, c1, c2)
        // quad allreduce (dirs live in lanes 4k..4k+3)
        sP.x += __shfl_xor(sP.x, 1, 64); sP.x += __shfl_xor(sP.x, 2, 64);
        sP.y += __shfl_xor(sP.y, 1, 64); sP.y += __shfl_xor(sP.y, 2, 64);
        sQ.x += __shfl_xor(sQ.x, 1, 64); sQ.x += __shfl_xor(sQ.x, 2, 64);
        sQ.y += __shfl_xor(sQ.y, 1, 64); sQ.y += __shfl_xor(sQ.y, 2, 64);
        const float b = s_l1b[o];
        float s0 = sP.x + b, s1 = sP.y + b, s2 = sQ.x + b, s3 = sQ.y + b;
        s0 = (s0 > 0.0f) ? SC * s0 : SC * AL * (fexp(s0) - 1.0f);
        s1 = (s1 > 0.0f) ? SC * s1 : SC * AL * (fexp(s1) - 1.0f);
        s2 = (s2 > 0.0f) ? SC * s2 : SC * AL * (fexp(s2) - 1.0f);
        s3 = (s3 > 0.0f) ? SC * s3 : SC * AL * (fexp(s3) - 1.0f);
        f32x2 suP = (f32x2){s0, s1}, suQ = (f32x2){s2, s3};
        o0P = pk_fma(suP, s_l2w2[0][o], o0P);
        o1P = pk_fma(suP, s_l2w2[1][o], o1P);
        o0Q = pk_fma(suQ, s_l2w2[0][o], o0Q);
        o1Q = pk_fma(suQ, s_l2w2[1][o], o1Q);
    }
    o0P.x = fminf(1.0f, fmaxf(-1.0f, o0P.x)); o0P.y = fminf(1.0f, fmaxf(-1.0f, o0P.y));
    o1P.x = fminf(1.0f, fmaxf(-1.0f, o1P.x)); o1P.y = fminf(1.0f, fmaxf(-1.0f, o1P.y));
    o0Q.x = fminf(1.0f, fmaxf(-1.0f, o0Q.x)); o0Q.y = fminf(1.0f, fmaxf(-1.0f, o0Q.y));
    o1Q.x = fminf(1.0f, fmaxf(-1.0f, o1Q.x)); o1Q.y = fminf(1.0f, fmaxf(-1.0f, o1Q.y));

    if (d == 0) {
        if (v01) *reinterpret_cast<float4*>(out + base * 2) = make_float4(o0P.x, o1P.x, o0P.y, o1P.y);
        if (v23) *reinterpret_cast<float4*>(out + base * 2 + 4) = make_float4(o0Q.x, o1Q.x, o0Q.y, o1Q.y);
        if (!v01 || !v23) {   // tail (unused at B=2^21, kept for generality)
            if (r0 < Btot && !v01) reinterpret_cast<float2*>(out)[r0] = make_float2(o0P.x, o1P.x);
            if (r2 < Btot && !v23) reinterpret_cast<float2*>(out)[r2] = make_float2(o0Q.x, o1Q.x);
        }
    }
}

extern "C" void kernel_launch(void* const* d_in, const int* in_sizes, int n_in,
                              void* d_out, int out_size, void* d_ws, size_t ws_size,
                              hipStream_t stream) {
    const float* state = (const float*)d_in[0];
    const int B = in_sizes[0] / 10;
    const int grid = (B + 255) / 256;   // 256 rows per 256-thread block (4 rows per lane-quad)

    actor_kernel<<<grid, 256, 0, stream>>>(
        state,
        (const float*)d_in[1],  (const float*)d_in[2],  (const float*)d_in[3],  (const float*)d_in[4],
        (const float*)d_in[5],  (const float*)d_in[6],  (const float*)d_in[7],  (const float*)d_in[8],
        (const float*)d_in[9],  (const float*)d_in[10], (const float*)d_in[11], (const float*)d_in[12],
        (const float*)d_in[13], (const float*)d_in[14], (const float*)d_in[15], (const float*)d_in[16],
        (const float*)d_in[17], (const float*)d_in[18], (const float*)d_in[19], (const float*)d_in[20],
        (float*)d_out, B);
}